// Round 8
// baseline (57.433 us; speedup 1.0000x reference)
//
#include <hip/hip_runtime.h>
#include <math.h>

#define NQ 10
#define DIM 1024
#define HID 64
#define NT 256

template<int CTRL>
__device__ __forceinline__ float fdpp(float v) {
    return __int_as_float(__builtin_amdgcn_update_dpp(
        0, __float_as_int(v), CTRL, 0xF, 0xF, true));
}
__device__ __forceinline__ float bperm(int a4, float v) {
    return __int_as_float(__builtin_amdgcn_ds_bpermute(a4, __float_as_int(v)));
}

// fused RY*RX 2x2 complex gate (validated r4/r6)
__device__ __forceinline__ void l1pair(float4 g, float& r0, float& i0, float& r1, float& i1) {
    float n0r = g.x * r0 - g.y * i0 - g.z * r1 + g.w * i1;
    float n0i = g.x * i0 + g.y * r0 - g.z * i1 - g.w * r1;
    float n1r = g.z * r0 + g.w * i0 + g.x * r1 + g.y * i1;
    float n1i = g.z * i0 - g.w * r0 + g.x * i1 - g.y * r1;
    r0 = n0r; i0 = n0i; r1 = n1r; i1 = n1i;
}
__device__ __forceinline__ void l2pair(float2 g, float& r0, float& i0, float& r1, float& i1) {
    float n0r = g.x * r0 - g.y * r1, n0i = g.x * i0 - g.y * i1;
    float n1r = g.y * r0 + g.x * r1, n1i = g.y * i0 + g.x * i1;
    r0 = n0r; i0 = n0i; r1 = n1r; i1 = n1i;
}

template<int P>
__device__ __forceinline__ void lane_gate_l1(float4 g, int lane, float (&vr)[16], float (&vi)[16]) {
    const float fsb = ((lane >> P) & 1) ? 1.f : -1.f;
    const float Bs = fsb * g.y, Cs = fsb * g.z;
    const int a4 = (lane ^ (1 << P)) << 2;
    #pragma unroll
    for (int r = 0; r < 16; r++) {
        float ur, ui;
        if constexpr (P == 0)      { ur = fdpp<0xB1>(vr[r]); ui = fdpp<0xB1>(vi[r]); }
        else if constexpr (P == 1) { ur = fdpp<0x4E>(vr[r]); ui = fdpp<0x4E>(vi[r]); }
        else                       { ur = bperm(a4, vr[r]);  ui = bperm(a4, vi[r]); }
        float nr = g.x * vr[r] + Bs * vi[r] + Cs * ur + g.w * ui;
        float ni = g.x * vi[r] - Bs * vr[r] + Cs * ui - g.w * ur;
        vr[r] = nr; vi[r] = ni;
    }
}
template<int P>
__device__ __forceinline__ void lane_gate_l2(float2 g, int lane, float (&vr)[16], float (&vi)[16]) {
    const float fsb = ((lane >> P) & 1) ? 1.f : -1.f;
    const float ssf = fsb * g.y;
    const int a4 = (lane ^ (1 << P)) << 2;
    #pragma unroll
    for (int r = 0; r < 16; r++) {
        float ur, ui;
        if constexpr (P == 0)      { ur = fdpp<0xB1>(vr[r]); ui = fdpp<0xB1>(vi[r]); }
        else if constexpr (P == 1) { ur = fdpp<0x4E>(vr[r]); ui = fdpp<0x4E>(vi[r]); }
        else                       { ur = bperm(a4, vr[r]);  ui = bperm(a4, vi[r]); }
        vr[r] = g.x * vr[r] + ssf * ur;
        vi[r] = g.x * vi[r] + ssf * ui;
    }
}

// ---- obs partial sums (validated r6) ----
template<int HB, int CM>
__device__ __forceinline__ float obs_halved(const float (&vr)[16], const float (&vi)[16],
                                            const char* stb, int base_cx, int w1) {
    float a0 = 0.f, a1 = 0.f;
    #pragma unroll
    for (int idx = 0; idx < 8; idx++) {
        const int lo = idx & ((1 << HB) - 1);
        const int r  = ((idx >> HB) << (HB + 1)) | lo;      // compile-time
        const float2 c = *(const float2*)(stb + (base_cx ^ (r << 9)));
        float t;
        if constexpr (CM) t = vr[r] * c.y - vi[r] * c.x;    // odd nY
        else              t = vr[r] * c.x + vi[r] * c.y;    // even nY
        const int cf = 0x40000000 | (((w1 >> r) & 1) << 31);
        if (idx & 1) a1 = fmaf(__int_as_float(cf), t, a1);
        else         a0 = fmaf(__int_as_float(cf), t, a0);
    }
    return a0 + a1;
}
template<int CM>
__device__ __forceinline__ float obs_full(const float (&vr)[16], const float (&vi)[16],
                                          const char* stb, int base_c, int w1) {
    float a0 = 0.f, a1 = 0.f;
    #pragma unroll
    for (int r = 0; r < 16; r++) {
        const float2 c = *(const float2*)(stb + base_c + (r << 9));
        float t;
        if constexpr (CM) t = vr[r] * c.y - vi[r] * c.x;
        else              t = vr[r] * c.x + vi[r] * c.y;
        const int cf = 0x3F800000 | (((w1 >> r) & 1) << 31);
        if (r & 1) a1 = fmaf(__int_as_float(cf), t, a1);
        else       a0 = fmaf(__int_as_float(cf), t, a0);
    }
    return a0 + a1;
}
__device__ __forceinline__ float obs_diag(const float (&vr)[16], const float (&vi)[16], int w1) {
    float a0 = 0.f, a1 = 0.f;
    #pragma unroll
    for (int r = 0; r < 16; r++) {
        float t = fmaf(vr[r], vr[r], vi[r] * vi[r]);
        const int cf = 0x3F800000 | (((w1 >> r) & 1) << 31);
        if (r & 1) a1 = fmaf(__int_as_float(cf), t, a1);
        else       a0 = fmaf(__int_as_float(cf), t, a0);
    }
    return a0 + a1;
}

// NOTE: (NT,2) not (NT,4): empirically (r5/r7) the 2nd arg=4 hard-caps VGPR at 64,
// which spills the 32-float state array to scratch (27 MB WRITE_SIZE, +6us).
// (NT,2) -> ~92 VGPR, still <=128 so HW can run 4 waves/SIMD.
__global__ __launch_bounds__(NT, 2) void qsa_kernel(
    const float* __restrict__ x,
    const float* __restrict__ rx0,
    const float* __restrict__ ry0,
    const float* __restrict__ ry1,
    const int*   __restrict__ op_codes,
    float* __restrict__ out)
{
    __shared__ float2 Sb[2][DIM];           // per-row shared state buffer (reused)
    __shared__ float  cb[4][64 * 17];       // per-wave transpose-reduce buffer
    __shared__ float4 s_l1[NQ];
    __shared__ float2 s_l2[NQ];
    __shared__ int4   s_meta[HID];          // xm, yzm&63, w1, hbc|cm<<3

    const int tid  = threadIdx.x;
    const int lane = tid & 63;
    const int wave = tid >> 6;
    const int H    = wave & 1;              // obs half this wave owns
    const int rp   = wave >> 1;             // row slot in block
    const int row  = blockIdx.x * 2 + rp;   // rows = 2048, grid = 1024: always valid
    const int rb8  = rp << 13;              // byte base of row's state buffer

    // ---- setup tables (block-shared, validated r6) ----
    if (tid < NQ) {
        float a = 0.5f * rx0[tid], b = 0.5f * ry0[tid];
        float c1 = cosf(a), s1 = sinf(a), c2 = cosf(b), s2 = sinf(b);
        s_l1[tid] = make_float4(c1 * c2, s1 * s2, s2 * c1, c2 * s1);  // A,B,C,D
    } else if (tid < 2 * NQ) {
        float a = 0.5f * ry1[tid - NQ];
        s_l2[tid - NQ] = make_float2(cosf(a), sinf(a));
    }
    if (tid >= 64 && tid < 64 + HID) {
        const int o = tid - 64;
        int xm = 0, yzm = 0, ny = 0;
        #pragma unroll
        for (int q = 0; q < NQ; q++) {
            int code = op_codes[o * NQ + q];
            int bit  = 1 << (NQ - 1 - q);       // qubit q = element bit 9-q
            if (code == 1) xm |= bit;
            else if (code == 2) { xm |= bit; yzm |= bit; ny++; }
            else if (code == 3) yzm |= bit;
        }
        const int cm = ny & 1, gflip = (ny >> 1) & 1;
        const int yh = yzm >> 6;
        int w1 = 0;
        #pragma unroll
        for (int r = 0; r < 16; r++)
            w1 |= ((__popc(r & yh) & 1) ^ gflip) << r;
        const int xmr = (xm >> 6) & 15;
        int hbc;
        if (xm == 0)      hbc = 5;              // diagonal
        else if (xmr)     hbc = __ffs(xmr) - 1; // halved on reg bit 0..3
        else              hbc = 4;              // lane-only xm: full 16
        s_meta[o] = make_int4(xm, yzm & 63, w1, hbc | (cm << 3));
    }

    // ---- load full row + normalize (identical on both waves of the row) ----
    float vr[16], vi[16];
    {
        const float* xr = x + (size_t)row * DIM;
        float ssq = 0.f;
        #pragma unroll
        for (int r = 0; r < 16; r++) {
            vr[r] = xr[(r << 6) + lane];
            vi[r] = 0.f;
            ssq += vr[r] * vr[r];
        }
        #pragma unroll
        for (int off = 32; off; off >>= 1) ssq += __shfl_xor(ssq, off, 64);
        const float inv = 1.0f / sqrtf(ssq);
        #pragma unroll
        for (int r = 0; r < 16; r++) vr[r] *= inv;
    }

    __syncthreads();                                 // B0: tables visible

    // ---- layer 1: reg-bit gates then lane-bit gates (validated r4/r6) ----
    #pragma unroll
    for (int j = 0; j < 4; j++) {
        const float4 g = s_l1[j];
        const int m = 1 << (3 - j);
        #pragma unroll
        for (int r = 0; r < 16; r++)
            if (!(r & m)) l1pair(g, vr[r], vi[r], vr[r | m], vi[r | m]);
    }
    lane_gate_l1<5>(s_l1[4], lane, vr, vi);
    lane_gate_l1<4>(s_l1[5], lane, vr, vi);
    lane_gate_l1<3>(s_l1[6], lane, vr, vi);
    lane_gate_l1<2>(s_l1[7], lane, vr, vi);
    lane_gate_l1<1>(s_l1[8], lane, vr, vi);
    lane_gate_l1<0>(s_l1[9], lane, vr, vi);

    // ---- CNOT ring via shared row buffer (only H==0 writes) ----
    if (H == 0) {
        #pragma unroll
        for (int r = 0; r < 16; r++) Sb[rp][(r << 6) | lane] = make_float2(vr[r], vi[r]);
    }
    __syncthreads();                                 // B1: Sb holds post-layer1
    #pragma unroll
    for (int r = 0; r < 16; r++) {
        int d = (r << 6) | lane;
        int src = (d ^ (d >> 1)) ^ ((d & 1) * 0x300);
        float2 t = Sb[rp][src];
        vr[r] = t.x; vi[r] = t.y;
    }
    __syncthreads();                                 // B2: gathers done, safe to overwrite

    // ---- layer 2 (RY) ----
    #pragma unroll
    for (int j = 0; j < 4; j++) {
        const float2 g = s_l2[j];
        const int m = 1 << (3 - j);
        #pragma unroll
        for (int r = 0; r < 16; r++)
            if (!(r & m)) l2pair(g, vr[r], vi[r], vr[r | m], vi[r | m]);
    }
    lane_gate_l2<5>(s_l2[4], lane, vr, vi);
    lane_gate_l2<4>(s_l2[5], lane, vr, vi);
    lane_gate_l2<3>(s_l2[6], lane, vr, vi);
    lane_gate_l2<2>(s_l2[7], lane, vr, vi);
    lane_gate_l2<1>(s_l2[8], lane, vr, vi);
    lane_gate_l2<0>(s_l2[9], lane, vr, vi);

    // ---- final-state mirror (shared, only H==0 writes) ----
    if (H == 0) {
        #pragma unroll
        for (int r = 0; r < 16; r++) Sb[rp][(r << 6) | lane] = make_float2(vr[r], vi[r]);
    }
    __syncthreads();                                 // B3: mirror ready

    // ---- observables: this wave owns obs H*32 .. H*32+31 ----
    const char* stb = (const char*)Sb;
    float* cbw = &cb[wave][lane * 17];
    const float* cbr = &cb[wave][(lane >> 4) * (16 * 17) + (lane & 15)];
    float res = 0.f;
    #pragma unroll 1
    for (int oo = 0; oo < 32; oo++) {
        const int o = (H << 5) + oo;
        int4 mt = s_meta[o];
        const int xm   = __builtin_amdgcn_readfirstlane(mt.x);
        const int yzml = __builtin_amdgcn_readfirstlane(mt.y);
        const int w1   = __builtin_amdgcn_readfirstlane(mt.z);
        const int knd  = __builtin_amdgcn_readfirstlane(mt.w);
        const int hbc = knd & 7, cm = knd >> 3;
        float p;
        if (hbc == 5) {
            p = obs_diag(vr, vi, w1);
        } else {
            const int xml = xm & 63, xmr = (xm >> 6) & 15;
            const int base_cx = rb8 | (xmr << 9) | ((lane ^ xml) << 3);
            switch (hbc | (cm << 3)) {
                case 0:     p = obs_halved<0,0>(vr, vi, stb, base_cx, w1); break;
                case 1:     p = obs_halved<1,0>(vr, vi, stb, base_cx, w1); break;
                case 2:     p = obs_halved<2,0>(vr, vi, stb, base_cx, w1); break;
                case 3:     p = obs_halved<3,0>(vr, vi, stb, base_cx, w1); break;
                case 4:     p = obs_full<0>(vr, vi, stb, base_cx, w1);     break;
                case 8 | 0: p = obs_halved<0,1>(vr, vi, stb, base_cx, w1); break;
                case 8 | 1: p = obs_halved<1,1>(vr, vi, stb, base_cx, w1); break;
                case 8 | 2: p = obs_halved<2,1>(vr, vi, stb, base_cx, w1); break;
                case 8 | 3: p = obs_halved<3,1>(vr, vi, stb, base_cx, w1); break;
                default:    p = obs_full<1>(vr, vi, stb, base_cx, w1);     break;
            }
        }
        const int sl = __popc(lane & yzml) & 1;
        p = __int_as_float(__float_as_int(p) ^ (sl << 31));
        cbw[oo & 15] = p;                       // 1 LDS write, no butterfly
        if ((oo & 15) == 15) {                  // drain chunk of 16 obs
            const int c = oo >> 4;              // 0 or 1
            float s0 = 0.f, s1 = 0.f, s2 = 0.f, s3 = 0.f;
            #pragma unroll
            for (int k = 0; k < 16; k += 4) {
                s0 += cbr[(k + 0) * 17];
                s1 += cbr[(k + 1) * 17];
                s2 += cbr[(k + 2) * 17];
                s3 += cbr[(k + 3) * 17];
            }
            float tot = (s0 + s1) + (s2 + s3);  // quarter-sum for obs (lane&15)
            tot += __shfl_xor(tot, 16, 64);
            tot += __shfl_xor(tot, 32, 64);     // full 64-lane sum
            if ((lane >> 4) == c) res = tot;    // local obs index == lane (0..31)
        }
    }
    if (lane < 32)
        out[(size_t)row * HID + (H << 5) + lane] = res;
}

extern "C" void kernel_launch(void* const* d_in, const int* in_sizes, int n_in,
                              void* d_out, int out_size, void* d_ws, size_t ws_size,
                              hipStream_t stream) {
    const float* x   = (const float*)d_in[0];
    const float* rx0 = (const float*)d_in[1];
    const float* ry0 = (const float*)d_in[2];
    const float* ry1 = (const float*)d_in[3];
    const int*   op  = (const int*)d_in[4];
    float* o = (float*)d_out;
    const int rows = in_sizes[0] / DIM;    // B*T = 2048
    qsa_kernel<<<rows / 2, NT, 0, stream>>>(x, rx0, ry0, ry1, op, o);
}

// Round 12
// 46.033 us; speedup vs baseline: 1.2476x; 1.2476x over previous
//
#include <hip/hip_runtime.h>
#include <math.h>

#define NQ 10
#define DIM 1024
#define HID 64
#define NT 64

template<int CTRL>
__device__ __forceinline__ float fdpp(float v) {
    return __int_as_float(__builtin_amdgcn_update_dpp(
        0, __float_as_int(v), CTRL, 0xF, 0xF, true));
}
__device__ __forceinline__ float bperm(int a4, float v) {
    return __int_as_float(__builtin_amdgcn_ds_bpermute(a4, __float_as_int(v)));
}

// fused RY*RX 2x2 complex gate (validated r4/r6)
__device__ __forceinline__ void l1pair(float4 g, float& r0, float& i0, float& r1, float& i1) {
    float n0r = g.x * r0 - g.y * i0 - g.z * r1 + g.w * i1;
    float n0i = g.x * i0 + g.y * r0 - g.z * i1 - g.w * r1;
    float n1r = g.z * r0 + g.w * i0 + g.x * r1 + g.y * i1;
    float n1i = g.z * i0 - g.w * r0 + g.x * i1 - g.y * r1;
    r0 = n0r; i0 = n0i; r1 = n1r; i1 = n1i;
}
__device__ __forceinline__ void l2pair(float2 g, float& r0, float& i0, float& r1, float& i1) {
    float n0r = g.x * r0 - g.y * r1, n0i = g.x * i0 - g.y * i1;
    float n1r = g.y * r0 + g.x * r1, n1i = g.y * i0 + g.x * i1;
    r0 = n0r; i0 = n0i; r1 = n1r; i1 = n1i;
}

template<int P>
__device__ __forceinline__ void lane_gate_l1(float4 g, int lane, float (&vr)[16], float (&vi)[16]) {
    const float fsb = ((lane >> P) & 1) ? 1.f : -1.f;
    const float Bs = fsb * g.y, Cs = fsb * g.z;
    const int a4 = (lane ^ (1 << P)) << 2;
    #pragma unroll
    for (int r = 0; r < 16; r++) {
        float ur, ui;
        if constexpr (P == 0)      { ur = fdpp<0xB1>(vr[r]); ui = fdpp<0xB1>(vi[r]); }
        else if constexpr (P == 1) { ur = fdpp<0x4E>(vr[r]); ui = fdpp<0x4E>(vi[r]); }
        else                       { ur = bperm(a4, vr[r]);  ui = bperm(a4, vi[r]); }
        float nr = g.x * vr[r] + Bs * vi[r] + Cs * ur + g.w * ui;
        float ni = g.x * vi[r] - Bs * vr[r] + Cs * ui - g.w * ur;
        vr[r] = nr; vi[r] = ni;
    }
}
template<int P>
__device__ __forceinline__ void lane_gate_l2(float2 g, int lane, float (&vr)[16], float (&vi)[16]) {
    const float fsb = ((lane >> P) & 1) ? 1.f : -1.f;
    const float ssf = fsb * g.y;
    const int a4 = (lane ^ (1 << P)) << 2;
    #pragma unroll
    for (int r = 0; r < 16; r++) {
        float ur, ui;
        if constexpr (P == 0)      { ur = fdpp<0xB1>(vr[r]); ui = fdpp<0xB1>(vi[r]); }
        else if constexpr (P == 1) { ur = fdpp<0x4E>(vr[r]); ui = fdpp<0x4E>(vi[r]); }
        else                       { ur = bperm(a4, vr[r]);  ui = bperm(a4, vi[r]); }
        vr[r] = g.x * vr[r] + ssf * ur;
        vi[r] = g.x * vi[r] + ssf * ui;
    }
}

// ---- obs partial sums (validated r6, verbatim; wb8 folded to 0) ----
template<int HB, int CM>
__device__ __forceinline__ float obs_halved(const float (&vr)[16], const float (&vi)[16],
                                            const char* stb, int base_cx, int w1) {
    float a0 = 0.f, a1 = 0.f;
    #pragma unroll
    for (int idx = 0; idx < 8; idx++) {
        const int lo = idx & ((1 << HB) - 1);
        const int r  = ((idx >> HB) << (HB + 1)) | lo;      // compile-time
        const float2 c = *(const float2*)(stb + (base_cx ^ (r << 9)));
        float t;
        if constexpr (CM) t = vr[r] * c.y - vi[r] * c.x;    // odd nY
        else              t = vr[r] * c.x + vi[r] * c.y;    // even nY
        const int cf = 0x40000000 | (((w1 >> r) & 1) << 31);
        if (idx & 1) a1 = fmaf(__int_as_float(cf), t, a1);
        else         a0 = fmaf(__int_as_float(cf), t, a0);
    }
    return a0 + a1;
}
template<int CM>
__device__ __forceinline__ float obs_full(const float (&vr)[16], const float (&vi)[16],
                                          const char* stb, int base_c, int w1) {
    float a0 = 0.f, a1 = 0.f;
    #pragma unroll
    for (int r = 0; r < 16; r++) {
        const float2 c = *(const float2*)(stb + base_c + (r << 9));
        float t;
        if constexpr (CM) t = vr[r] * c.y - vi[r] * c.x;
        else              t = vr[r] * c.x + vi[r] * c.y;
        const int cf = 0x3F800000 | (((w1 >> r) & 1) << 31);
        if (r & 1) a1 = fmaf(__int_as_float(cf), t, a1);
        else       a0 = fmaf(__int_as_float(cf), t, a0);
    }
    return a0 + a1;
}
__device__ __forceinline__ float obs_diag(const float (&vr)[16], const float (&vi)[16], int w1) {
    float a0 = 0.f, a1 = 0.f;
    #pragma unroll
    for (int r = 0; r < 16; r++) {
        float t = fmaf(vr[r], vr[r], vi[r] * vi[r]);
        const int cf = 0x3F800000 | (((w1 >> r) & 1) << 31);
        if (r & 1) a1 = fmaf(__int_as_float(cf), t, a1);
        else       a0 = fmaf(__int_as_float(cf), t, a0);
    }
    return a0 + a1;
}

// 1 wave per block: LDS/block ~14.5 KB -> ~11 blocks/CU (vs r6's grid-capped ~6
// waves/CU at 51.7 KB blocks). (64,4) caps VGPR at 128 (r6 body needs ~92).
__global__ __launch_bounds__(NT, 4) void qsa_kernel(
    const float* __restrict__ x,
    const float* __restrict__ rx0,
    const float* __restrict__ ry0,
    const float* __restrict__ ry1,
    const int*   __restrict__ op_codes,
    float* __restrict__ out)
{
    __shared__ float2 st[DIM];              // this wave's state (8 KB)
    __shared__ float  cb[64 * 17];          // transpose-reduce buffer (r6)
    __shared__ float4 s_l1[NQ];
    __shared__ float2 s_l2[NQ];
    __shared__ int4   s_meta[HID];          // xm, yzm&63, w1, hbc|cm<<3

    const int lane = threadIdx.x;
    const int row  = blockIdx.x;            // 0..2047

    // ---- setup tables (one wave: lanes 0-9 l1, 10-19 l2, all lanes meta) ----
    if (lane < NQ) {
        float a = 0.5f * rx0[lane], b = 0.5f * ry0[lane];
        float c1 = cosf(a), s1 = sinf(a), c2 = cosf(b), s2 = sinf(b);
        s_l1[lane] = make_float4(c1 * c2, s1 * s2, s2 * c1, c2 * s1);  // A,B,C,D
    } else if (lane < 2 * NQ) {
        float a = 0.5f * ry1[lane - NQ];
        s_l2[lane - NQ] = make_float2(cosf(a), sinf(a));
    }
    {
        const int o = lane;                 // lane o builds meta for obs o
        int xm = 0, yzm = 0, ny = 0;
        #pragma unroll
        for (int q = 0; q < NQ; q++) {
            int code = op_codes[o * NQ + q];
            int bit  = 1 << (NQ - 1 - q);       // qubit q = element bit 9-q
            if (code == 1) xm |= bit;
            else if (code == 2) { xm |= bit; yzm |= bit; ny++; }
            else if (code == 3) yzm |= bit;
        }
        const int cm = ny & 1, gflip = (ny >> 1) & 1;
        const int yh = yzm >> 6;
        int w1 = 0;
        #pragma unroll
        for (int r = 0; r < 16; r++)
            w1 |= ((__popc(r & yh) & 1) ^ gflip) << r;
        const int xmr = (xm >> 6) & 15;
        int hbc;
        if (xm == 0)      hbc = 5;              // diagonal
        else if (xmr)     hbc = __ffs(xmr) - 1; // halved on reg bit 0..3
        else              hbc = 4;              // lane-only xm: full 16
        s_meta[o] = make_int4(xm, yzm & 63, w1, hbc | (cm << 3));
    }

    // ---- load + normalize (registers/shfl only) ----
    float vr[16], vi[16];
    {
        const float* xr = x + (size_t)row * DIM;
        float ssq = 0.f;
        #pragma unroll
        for (int r = 0; r < 16; r++) {
            vr[r] = xr[(r << 6) + lane];
            vi[r] = 0.f;
            ssq += vr[r] * vr[r];
        }
        #pragma unroll
        for (int off = 32; off; off >>= 1) ssq += __shfl_xor(ssq, off, 64);
        const float inv = 1.0f / sqrtf(ssq);
        #pragma unroll
        for (int r = 0; r < 16; r++) vr[r] *= inv;
    }

    __syncthreads();            // publish tables (near-free in 1-wave block)

    // ---- layer 1: qubits 0..3 on reg-bits 3..0, 4..9 on lane-bits 5..0 (r6) ----
    #pragma unroll
    for (int j = 0; j < 4; j++) {
        const float4 g = s_l1[j];
        const int m = 1 << (3 - j);
        #pragma unroll
        for (int r = 0; r < 16; r++)
            if (!(r & m)) l1pair(g, vr[r], vi[r], vr[r | m], vi[r | m]);
    }
    lane_gate_l1<5>(s_l1[4], lane, vr, vi);
    lane_gate_l1<4>(s_l1[5], lane, vr, vi);
    lane_gate_l1<3>(s_l1[6], lane, vr, vi);
    lane_gate_l1<2>(s_l1[7], lane, vr, vi);
    lane_gate_l1<1>(s_l1[8], lane, vr, vi);
    lane_gate_l1<0>(s_l1[9], lane, vr, vi);

    // ---- CNOT ring: composed permutation gather (wave-private) ----
    #pragma unroll
    for (int r = 0; r < 16; r++) st[(r << 6) | lane] = make_float2(vr[r], vi[r]);
    #pragma unroll
    for (int r = 0; r < 16; r++) {
        int d = (r << 6) | lane;
        int src = (d ^ (d >> 1)) ^ ((d & 1) * 0x300);
        float2 t = st[src];
        vr[r] = t.x; vi[r] = t.y;
    }

    // ---- layer 2 (RY) ----
    #pragma unroll
    for (int j = 0; j < 4; j++) {
        const float2 g = s_l2[j];
        const int m = 1 << (3 - j);
        #pragma unroll
        for (int r = 0; r < 16; r++)
            if (!(r & m)) l2pair(g, vr[r], vi[r], vr[r | m], vi[r | m]);
    }
    lane_gate_l2<5>(s_l2[4], lane, vr, vi);
    lane_gate_l2<4>(s_l2[5], lane, vr, vi);
    lane_gate_l2<3>(s_l2[6], lane, vr, vi);
    lane_gate_l2<2>(s_l2[7], lane, vr, vi);
    lane_gate_l2<1>(s_l2[8], lane, vr, vi);
    lane_gate_l2<0>(s_l2[9], lane, vr, vi);

    // ---- final-state mirror (c-side source) ----
    #pragma unroll
    for (int r = 0; r < 16; r++) st[(r << 6) | lane] = make_float2(vr[r], vi[r]);

    // ---- observables: a-side regs, c-side LDS; chunked-transpose drain (r6) ----
    const char* stb = (const char*)st;
    float* cbw = &cb[lane * 17];
    const float* cbr = &cb[(lane >> 4) * (16 * 17) + (lane & 15)];
    float res = 0.f;
    #pragma unroll 1
    for (int o = 0; o < HID; o++) {
        int4 mt = s_meta[o];
        const int xm   = __builtin_amdgcn_readfirstlane(mt.x);
        const int yzml = __builtin_amdgcn_readfirstlane(mt.y);
        const int w1   = __builtin_amdgcn_readfirstlane(mt.z);
        const int knd  = __builtin_amdgcn_readfirstlane(mt.w);
        const int hbc = knd & 7, cm = knd >> 3;
        float p;
        if (hbc == 5) {
            p = obs_diag(vr, vi, w1);
        } else {
            const int xml = xm & 63, xmr = (xm >> 6) & 15;
            const int base_cx = (xmr << 9) | ((lane ^ xml) << 3);
            switch (hbc | (cm << 3)) {
                case 0:     p = obs_halved<0,0>(vr, vi, stb, base_cx, w1); break;
                case 1:     p = obs_halved<1,0>(vr, vi, stb, base_cx, w1); break;
                case 2:     p = obs_halved<2,0>(vr, vi, stb, base_cx, w1); break;
                case 3:     p = obs_halved<3,0>(vr, vi, stb, base_cx, w1); break;
                case 4:     p = obs_full<0>(vr, vi, stb, base_cx, w1);     break;
                case 8 | 0: p = obs_halved<0,1>(vr, vi, stb, base_cx, w1); break;
                case 8 | 1: p = obs_halved<1,1>(vr, vi, stb, base_cx, w1); break;
                case 8 | 2: p = obs_halved<2,1>(vr, vi, stb, base_cx, w1); break;
                case 8 | 3: p = obs_halved<3,1>(vr, vi, stb, base_cx, w1); break;
                default:    p = obs_full<1>(vr, vi, stb, base_cx, w1);     break;
            }
        }
        const int sl = __popc(lane & yzml) & 1;
        p = __int_as_float(__float_as_int(p) ^ (sl << 31));
        cbw[o & 15] = p;                        // 1 LDS write, no butterfly
        if ((o & 15) == 15) {                   // drain chunk of 16 obs
            const int c = o >> 4;
            float s0 = 0.f, s1 = 0.f, s2 = 0.f, s3 = 0.f;
            #pragma unroll
            for (int k = 0; k < 16; k += 4) {
                s0 += cbr[(k + 0) * 17];
                s1 += cbr[(k + 1) * 17];
                s2 += cbr[(k + 2) * 17];
                s3 += cbr[(k + 3) * 17];
            }
            float tot = (s0 + s1) + (s2 + s3);  // quarter-sum for obs lane&15
            tot += __shfl_xor(tot, 16, 64);
            tot += __shfl_xor(tot, 32, 64);     // full 64-lane sum
            if ((lane >> 4) == c) res = tot;    // this lane's obs is in chunk c
        }
    }
    out[(size_t)row * HID + lane] = res;
}

extern "C" void kernel_launch(void* const* d_in, const int* in_sizes, int n_in,
                              void* d_out, int out_size, void* d_ws, size_t ws_size,
                              hipStream_t stream) {
    const float* x   = (const float*)d_in[0];
    const float* rx0 = (const float*)d_in[1];
    const float* ry0 = (const float*)d_in[2];
    const float* ry1 = (const float*)d_in[3];
    const int*   op  = (const int*)d_in[4];
    float* o = (float*)d_out;
    const int rows = in_sizes[0] / DIM;    // B*T = 2048
    qsa_kernel<<<rows, NT, 0, stream>>>(x, rx0, ry0, ry1, op, o);
}